// Round 6
// baseline (809.735 us; speedup 1.0000x reference)
//
#include <hip/hip_runtime.h>
#include <math.h>

constexpr int Bc = 8, Nc = 2048, Dc = 256;
constexpr int BN = Bc * Nc; // 16384

typedef __attribute__((ext_vector_type(8))) short short8;
typedef __attribute__((ext_vector_type(4))) float f32x4;

__device__ __forceinline__ float sigmoidf_(float x) { return 1.0f / (1.0f + expf(-x)); }

__device__ __forceinline__ unsigned short f2bf(float f) { // RNE fp32 -> bf16
    unsigned int u = __float_as_uint(f);
    u = (u + 0x7FFFu + ((u >> 16) & 1u)) >> 16;
    return (unsigned short)u;
}
__device__ __forceinline__ float bf2f(unsigned short s) {
    return __uint_as_float(((unsigned int)s) << 16);
}

// 8-elem bf16 fragment: elems 0..3 at base[0..3], elems 4..7 at base[16..19].
// k-slot bijection slot(g16,e): e<4 -> g16*4+e ; e>=4 -> 16+g16*4+(e-4).
// A and B both use it => consistent pairing (any bijection valid).
__device__ __forceinline__ short8 ld_frag(const unsigned short* base) {
    ushort4 lo = *(const ushort4*)(base);
    ushort4 hi = *(const ushort4*)(base + 16);
    short8 a;
    a[0] = (short)lo.x; a[1] = (short)lo.y; a[2] = (short)lo.z; a[3] = (short)lo.w;
    a[4] = (short)hi.x; a[5] = (short)hi.y; a[6] = (short)hi.z; a[7] = (short)hi.w;
    return a;
}
__device__ __forceinline__ f32x4 fz4() { f32x4 z = {0.f, 0.f, 0.f, 0.f}; return z; }

// ---------------- cast feat fp32 -> bf16 ----------------
__global__ __launch_bounds__(256) void cast_kernel(const float* __restrict__ f,
                                                   unsigned short* __restrict__ o) {
    int i = (blockIdx.x * 256 + threadIdx.x) * 4;
    float4 v = *(const float4*)(f + i);
    ushort4 u = {f2bf(v.x), f2bf(v.y), f2bf(v.z), f2bf(v.w)};
    *(ushort4*)(o + i) = u;
}

// ---------------- pack BmT[512 n][256 k] bf16 = [ W | Hw^T ]^T ----------------
__global__ __launch_bounds__(256) void pack_bt_kernel(const float* __restrict__ W,
                                                      const float* __restrict__ Hw,
                                                      unsigned short* __restrict__ BmT) {
    int idx = blockIdx.x * 256 + threadIdx.x;
    int o = idx >> 8, k = idx & 255;
    float v = (o < 256) ? W[k * 256 + o] : Hw[(o - 256) * 256 + k];
    BmT[idx] = f2bf(v);
}

// ---------------- MFMA GEMM: C(16384x512) = featb @ BmT^T ; h | gate epilogue ----------------
__global__ __launch_bounds__(256) void gemm_mfma(const unsigned short* __restrict__ featb,
                                                 const unsigned short* __restrict__ BmT,
                                                 const float* __restrict__ Hb,
                                                 float* __restrict__ h,
                                                 float* __restrict__ gate) {
    const int tid = threadIdx.x, lane = tid & 63, w = tid >> 6;
    const int g16 = lane >> 4, li = lane & 15;
    const int m0 = blockIdx.x * 64, nw = blockIdx.y * 128 + w * 32;
    f32x4 acc[4][2];
#pragma unroll
    for (int rf = 0; rf < 4; ++rf)
#pragma unroll
        for (int cf = 0; cf < 2; ++cf) acc[rf][cf] = fz4();
    for (int k0 = 0; k0 < 256; k0 += 32) {
        short8 Af[4];
#pragma unroll
        for (int rf = 0; rf < 4; ++rf)
            Af[rf] = ld_frag(featb + (size_t)(m0 + rf * 16 + li) * 256 + k0 + g16 * 4);
#pragma unroll
        for (int cf = 0; cf < 2; ++cf) {
            short8 Bf = ld_frag(BmT + (size_t)(nw + cf * 16 + li) * 256 + k0 + g16 * 4);
#pragma unroll
            for (int rf = 0; rf < 4; ++rf)
                acc[rf][cf] = __builtin_amdgcn_mfma_f32_16x16x32_bf16(Af[rf], Bf, acc[rf][cf], 0, 0, 0);
        }
    }
#pragma unroll
    for (int rf = 0; rf < 4; ++rf)
#pragma unroll
        for (int cf = 0; cf < 2; ++cf) {
            const int n = nw + cf * 16 + li;
#pragma unroll
            for (int reg = 0; reg < 4; ++reg) {
                const int m = m0 + rf * 16 + g16 * 4 + reg;
                float v = acc[rf][cf][reg];
                if (n < 256) h[(size_t)m * 256 + n] = v;
                else gate[(size_t)m * 256 + (n - 256)] = sigmoidf_(v + Hb[n - 256]);
            }
        }
}

// ---------------- transpose-cast h->hT  +  a_src/a_dst partial dots  +  mean partials ----------------
__global__ __launch_bounds__(256) void tr64f_kernel(const float* __restrict__ h,
                                                    const float* __restrict__ Ws,
                                                    unsigned short* __restrict__ hT,
                                                    float* __restrict__ a_src,
                                                    float* __restrict__ a_dst,
                                                    float* __restrict__ mean_h) {
    __shared__ float tile[64][65];
    const int j0 = blockIdx.x * 64, d0 = blockIdx.y * 64, b = blockIdx.z;
    const int tid = threadIdx.x;
#pragma unroll
    for (int p = 0; p < 16; ++p) {
        int idx = tid + p * 256;
        int jl = idx >> 6, dl = idx & 63;
        tile[jl][dl] = h[((size_t)b * Nc + j0 + jl) * 256 + d0 + dl];
    }
    __syncthreads();
#pragma unroll
    for (int p = 0; p < 16; ++p) {
        int idx = tid + p * 256;
        int dl = idx >> 6, jl = idx & 63;
        hT[((size_t)b * 256 + d0 + dl) * Nc + j0 + jl] = f2bf(tile[jl][dl]);
    }
    { // a_src/a_dst partial dot: thread = (row jl, quarter q of 16 d's)
        const int jl = tid >> 2, q = tid & 3;
        float s1 = 0.f, s2 = 0.f;
#pragma unroll
        for (int e = 0; e < 16; ++e) {
            const float hv = tile[jl][q * 16 + e];
            s1 = fmaf(hv, Ws[d0 + q * 16 + e], s1);
            s2 = fmaf(hv, Ws[256 + d0 + q * 16 + e], s2);
        }
        s1 += __shfl_xor(s1, 1); s1 += __shfl_xor(s1, 2);
        s2 += __shfl_xor(s2, 1); s2 += __shfl_xor(s2, 2);
        if (q == 0) {
            atomicAdd(&a_src[b * Nc + j0 + jl], s1);
            atomicAdd(&a_dst[b * Nc + j0 + jl], s2);
        }
    }
    { // mean partial: thread = (d-col dl, 16-row part)
        const int dl = tid & 63, part = tid >> 6;
        float sm = 0.f;
#pragma unroll
        for (int e = 0; e < 16; ++e) sm += tile[part * 16 + e][dl];
        atomicAdd(&mean_h[b * 256 + d0 + dl], sm);
    }
}

// ---------------- chunked fused score: P-in-register, no barriers; last chunk does epilogue+fill ----
constexpr int CHUNK = 8;
__global__ __launch_bounds__(256) void score_chunk(
    const int* __restrict__ adj, const unsigned short* __restrict__ hT,
    const float* __restrict__ a_src, const float* __restrict__ a_dst,
    const float* __restrict__ bs_p, const float* __restrict__ bvec,
    const float* __restrict__ gate, const float* __restrict__ feat,
    const float* __restrict__ mean_h, float* __restrict__ sArr,
    int* __restrict__ cnt, float* __restrict__ out1, float* __restrict__ out2) {
    __shared__ int sh_last;

    // decode block -> (b, ib, c)   [R4-proven]
    const int bid = blockIdx.x;
    const int b = bid & 7; // batch -> XCD affinity
    int t = bid >> 3;      // 0..287
    int g = 0;
    while (g < 7 && 4 * (g + 1) * (g + 2) <= t) ++g;
    const int r_ = t - 4 * g * (g + 1);
    const int ib = g * 8 + r_ / (g + 1);
    const int c = r_ % (g + 1);
    const int i0 = ib * 32;
    const int t0 = c * CHUNK;
    const int t1 = min(ib + 1, t0 + CHUNK);

    const int tid = threadIdx.x, lane = tid & 63, w = tid >> 6;
    const int g16 = lane >> 4, li = lane & 15;
    const float bsv = bs_p[0];
    const float as0 = a_src[b * Nc + i0 + li];
    const float as1 = a_src[b * Nc + i0 + 16 + li];

    const int* adjb = adj + (size_t)b * Nc * Nc;
    const float* adb = a_dst + b * Nc;
    const unsigned short* hTb = hT + (size_t)b * 256 * Nc;

    f32x4 acc[2][4];
#pragma unroll
    for (int rf = 0; rf < 2; ++rf)
#pragma unroll
        for (int cf = 0; cf < 4; ++cf) acc[rf][cf] = fz4();
    float rs0 = 0.f, rs1 = 0.f;

    for (int tt = t0; tt < t1; ++tt) {
        const int j0 = tt * 32;
        float4 ad0 = *(const float4*)(adb + j0 + g16 * 4);
        float4 ad1 = *(const float4*)(adb + j0 + 16 + g16 * 4);
        short8 A[2];
#pragma unroll
        for (int rf = 0; rf < 2; ++rf) {
            const int irow = i0 + rf * 16 + li;
            const float asr = rf ? as1 : as0;
            int4 aj0 = *(const int4*)(adjb + (size_t)irow * Nc + j0 + g16 * 4);
            int4 aj1 = *(const int4*)(adjb + (size_t)irow * Nc + j0 + 16 + g16 * 4);
            float4 o2lo, o2hi;
#pragma unroll
            for (int e = 0; e < 8; ++e) {
                const int j = j0 + ((e < 4) ? (g16 * 4 + e) : (16 + g16 * 4 + e - 4));
                const int a_ = (e < 4) ? ((const int*)&aj0)[e] : ((const int*)&aj1)[e - 4];
                const float adv = (e < 4) ? ((const float*)&ad0)[e] : ((const float*)&ad1)[e - 4];
                // fast sigmoid: 1/(1+exp(-x)) via native exp + rcp
                const float IA = -__builtin_amdgcn_rcpf(1.f + __expf(-(asr + adv + bsv)));
                float o2v, p;
                if (j > irow)       { o2v = 0.f; p = 0.f; }
                else if (j == irow) { o2v = 1.f; p = (a_ == 1) ? 1.f : 0.f; }
                else                { o2v = IA;  p = (a_ == 1) ? __expf(IA - 1.f) : 0.f; }
                const unsigned short pb = f2bf(p);
                A[rf][e] = (short)pb;
                const float pr = bf2f(pb);
                if (rf == 0) rs0 += pr; else rs1 += pr;
                if (e < 4) ((float*)&o2lo)[e] = o2v; else ((float*)&o2hi)[e - 4] = o2v;
            }
            if (w == 0) {
                *(float4*)(out2 + ((size_t)b * Nc + irow) * Nc + j0 + g16 * 4) = o2lo;
                *(float4*)(out2 + ((size_t)b * Nc + irow) * Nc + j0 + 16 + g16 * 4) = o2hi;
            }
        }
#pragma unroll
        for (int cf = 0; cf < 4; ++cf) {
            short8 Bf = ld_frag(hTb + (size_t)(w * 64 + cf * 16 + li) * Nc + j0 + g16 * 4);
            acc[0][cf] = __builtin_amdgcn_mfma_f32_16x16x32_bf16(A[0], Bf, acc[0][cf], 0, 0, 0);
            acc[1][cf] = __builtin_amdgcn_mfma_f32_16x16x32_bf16(A[1], Bf, acc[1][cf], 0, 0, 0);
        }
    }
    // row sums: reduce across g16 lane groups (disjoint k-slots)
    rs0 += __shfl_xor(rs0, 16); rs0 += __shfl_xor(rs0, 32);
    rs1 += __shfl_xor(rs1, 16); rs1 += __shfl_xor(rs1, 32);
    if (w == 0 && g16 == 0) {
        atomicAdd(&sArr[b * Nc + i0 + li], rs0);
        atomicAdd(&sArr[b * Nc + i0 + 16 + li], rs1);
    }
    // combine partial O
#pragma unroll
    for (int rf = 0; rf < 2; ++rf)
#pragma unroll
        for (int cf = 0; cf < 4; ++cf) {
            float* dst = out1 + ((size_t)b * Nc + i0 + rf * 16 + g16 * 4) * 256 + w * 64 + cf * 16 + li;
#pragma unroll
            for (int reg = 0; reg < 4; ++reg)
                atomicAdd(dst + (size_t)reg * 256, acc[rf][cf][reg]);
        }

    // ---- last-chunk-done: fused epilogue + upper-triangle fill ----
    __threadfence();
    if (tid == 0) sh_last = (atomicAdd(&cnt[b * 64 + ib], 1) == (ib >> 3));
    __syncthreads();
    if (!sh_last) return;

    const float invN = 1.0f / Nc;
    const int col = (tid & 63) * 4;
    const float4 b4 = *(const float4*)(bvec + col);
    const float4 mh4 = *(const float4*)(mean_h + b * 256 + col);
#pragma unroll
    for (int pass = 0; pass < 8; ++pass) {
        const int row = i0 + pass * 4 + (tid >> 6);
        const size_t gix = ((size_t)b * Nc + row) * 256 + col;
        const float s = __hip_atomic_load(&sArr[b * Nc + row], __ATOMIC_RELAXED, __HIP_MEMORY_SCOPE_AGENT);
        float v[4];
        if (s == 0.f) { // fully-masked row: softmax uniform over ALL N cols
            v[0] = mh4.x * invN; v[1] = mh4.y * invN; v[2] = mh4.z * invN; v[3] = mh4.w * invN;
        } else {
            const float inv = __builtin_amdgcn_rcpf(s);
#pragma unroll
            for (int k = 0; k < 4; ++k)
                v[k] = __hip_atomic_load(&out1[gix + k], __ATOMIC_RELAXED, __HIP_MEMORY_SCOPE_AGENT) * inv;
        }
        const float4 g4 = *(const float4*)(gate + gix);
        const float4 f4 = *(const float4*)(feat + gix);
        float4 o;
        {
            float vv = v[0] + b4.x; vv = vv > 0.f ? vv : __expf(vv) - 1.f;
            o.x = g4.x * vv + (1.f - g4.x) * f4.x;
        }
        {
            float vv = v[1] + b4.y; vv = vv > 0.f ? vv : __expf(vv) - 1.f;
            o.y = g4.y * vv + (1.f - g4.y) * f4.y;
        }
        {
            float vv = v[2] + b4.z; vv = vv > 0.f ? vv : __expf(vv) - 1.f;
            o.z = g4.z * vv + (1.f - g4.z) * f4.z;
        }
        {
            float vv = v[3] + b4.w; vv = vv > 0.f ? vv : __expf(vv) - 1.f;
            o.w = g4.w * vv + (1.f - g4.w) * f4.w;
        }
        *(float4*)(out1 + gix) = o;
    }
    { // zero-fill upper tail of I_A_raw (cols >= i0+32)
        const int jstart4 = (i0 + 32) >> 2;
        const float4 z = make_float4(0.f, 0.f, 0.f, 0.f);
        for (int r = 0; r < 32; ++r) {
            float4* rowp = (float4*)(out2 + ((size_t)b * Nc + i0 + r) * Nc);
            for (int j4 = jstart4 + tid; j4 < Nc / 4; j4 += 256) rowp[j4] = z;
        }
    }
}

extern "C" void kernel_launch(void* const* d_in, const int* in_sizes, int n_in,
                              void* d_out, int out_size, void* d_ws, size_t ws_size,
                              hipStream_t stream) {
    const float* feat = (const float*)d_in[0];
    const int* adj = (const int*)d_in[1];
    const float* W = (const float*)d_in[2];
    const float* bvec = (const float*)d_in[3];
    const float* Ws = (const float*)d_in[4];
    const float* bs = (const float*)d_in[5];
    const float* Hw = (const float*)d_in[6];
    const float* Hb = (const float*)d_in[7];

    float* ws = (float*)d_ws;
    unsigned short* featb = (unsigned short*)ws; // bf16 16384x256; reused as hT after gemm
    unsigned short* hT = featb;
    unsigned short* BmT = featb + 4194304;       // bf16 512x256
    float* h = ws + 2097152 + 65536;             // fp32 16384x256
    float* gate = h + 4194304;                   // fp32 16384x256
    float* a_src = gate + 4194304;               // 16384
    float* a_dst = a_src + 16384;                // 16384
    float* mean_h = a_dst + 16384;               // 2048
    float* sArr = mean_h + 2048;                 // 16384
    int* cnt = (int*)(sArr + 16384);             // 512

    float* out1 = (float*)d_out;
    float* out2 = out1 + (size_t)BN * 256;

    hipLaunchKernelGGL(cast_kernel, dim3(4096), dim3(256), 0, stream, feat, featb);
    hipLaunchKernelGGL(pack_bt_kernel, dim3(512), dim3(256), 0, stream, W, Hw, BmT);
    hipLaunchKernelGGL(gemm_mfma, dim3(256, 4), dim3(256), 0, stream, featb, BmT, Hb, h, gate);
    // zero a_src | a_dst | mean_h | sArr | cnt in one shot
    hipMemsetAsync(a_src, 0, (16384 + 16384 + 2048 + 16384 + 512) * sizeof(float), stream);
    hipLaunchKernelGGL(tr64f_kernel, dim3(32, 4, 8), dim3(256), 0, stream,
                       h, Ws, hT, a_src, a_dst, mean_h);
    hipMemsetAsync(out1, 0, (size_t)BN * 256 * sizeof(float), stream); // accO zero
    hipLaunchKernelGGL(score_chunk, dim3(2304), dim3(256), 0, stream,
                       adj, hT, a_src, a_dst, bs, bvec, gate, feat, mean_h,
                       sArr, cnt, out1, out2);
}

// Round 7
// 389.335 us; speedup vs baseline: 2.0798x; 2.0798x over previous
//
#include <hip/hip_runtime.h>
#include <math.h>

constexpr int Bc = 8, Nc = 2048, Dc = 256;
constexpr int BN = Bc * Nc; // 16384

typedef __attribute__((ext_vector_type(8))) short short8;
typedef __attribute__((ext_vector_type(4))) float f32x4;

__device__ __forceinline__ float sigmoidf_(float x) { return 1.0f / (1.0f + expf(-x)); }

__device__ __forceinline__ unsigned short f2bf(float f) { // RNE fp32 -> bf16
    unsigned int u = __float_as_uint(f);
    u = (u + 0x7FFFu + ((u >> 16) & 1u)) >> 16;
    return (unsigned short)u;
}
__device__ __forceinline__ float bf2f(unsigned short s) {
    return __uint_as_float(((unsigned int)s) << 16);
}

// 8-elem bf16 fragment: elems 0..3 at base[0..3], elems 4..7 at base[16..19].
// k-slot bijection slot(g16,e): e<4 -> g16*4+e ; e>=4 -> 16+g16*4+(e-4).
// A and B fragments both use it => consistent pairing (any bijection valid).
__device__ __forceinline__ short8 ld_frag(const unsigned short* base) {
    ushort4 lo = *(const ushort4*)(base);
    ushort4 hi = *(const ushort4*)(base + 16);
    short8 a;
    a[0] = (short)lo.x; a[1] = (short)lo.y; a[2] = (short)lo.z; a[3] = (short)lo.w;
    a[4] = (short)hi.x; a[5] = (short)hi.y; a[6] = (short)hi.z; a[7] = (short)hi.w;
    return a;
}
__device__ __forceinline__ f32x4 fz4() { f32x4 z = {0.f, 0.f, 0.f, 0.f}; return z; }

// lgkm-only barrier: drains LDS ops but NOT pending global stores/loads (vmcnt),
// so out2 stores and prefetches stay in flight across it. Rule #18: sched_barrier after.
__device__ __forceinline__ void lds_barrier() {
    asm volatile("s_waitcnt lgkmcnt(0)" ::: "memory");
    __builtin_amdgcn_s_barrier();
    __builtin_amdgcn_sched_barrier(0);
}

// ---------------- cast feat fp32 -> bf16 ----------------
__global__ __launch_bounds__(256) void cast_kernel(const float* __restrict__ f,
                                                   unsigned short* __restrict__ o) {
    int i = (blockIdx.x * 256 + threadIdx.x) * 4;
    float4 v = *(const float4*)(f + i);
    ushort4 u = {f2bf(v.x), f2bf(v.y), f2bf(v.z), f2bf(v.w)};
    *(ushort4*)(o + i) = u;
}

// ---------------- pack BmT[512 n][256 k] bf16 = [ W | Hw^T ]^T ----------------
__global__ __launch_bounds__(256) void pack_bt_kernel(const float* __restrict__ W,
                                                      const float* __restrict__ Hw,
                                                      unsigned short* __restrict__ BmT) {
    int idx = blockIdx.x * 256 + threadIdx.x;
    int o = idx >> 8, k = idx & 255;
    float v = (o < 256) ? W[k * 256 + o] : Hw[(o - 256) * 256 + k];
    BmT[idx] = f2bf(v);
}

// ---------------- LDS-staged MFMA GEMM: C(16384x512)=featb@BmT^T ; h|gate epilogue ------
__global__ __launch_bounds__(256) void gemm_lds(const unsigned short* __restrict__ featb,
                                                const unsigned short* __restrict__ BmT,
                                                const float* __restrict__ Hb,
                                                float* __restrict__ h,
                                                float* __restrict__ gate) {
    __shared__ unsigned short As[128][72]; // stride 72: 2-way-free LDS banks for b64 reads
    __shared__ unsigned short Bs[128][72];
    const int tid = threadIdx.x, lane = tid & 63, w = tid >> 6;
    const int g16 = lane >> 4, li = lane & 15;
    const int wr = w >> 1, wc = w & 1; // wave quadrant (64x64)
    const int m0 = blockIdx.x * 128, n0 = blockIdx.y * 128;
    const int srow = tid >> 1, sseg = (tid & 1) * 32; // staging row / k-seg
    f32x4 acc[4][4];
#pragma unroll
    for (int rf = 0; rf < 4; ++rf)
#pragma unroll
        for (int cf = 0; cf < 4; ++cf) acc[rf][cf] = fz4();
    for (int k0 = 0; k0 < 256; k0 += 64) {
        if (k0) __syncthreads();
#pragma unroll
        for (int q = 0; q < 4; ++q) { // coalesced stage A,B (16B per load)
            int4 va = *(const int4*)(featb + (size_t)(m0 + srow) * 256 + k0 + sseg + q * 8);
            *(int4*)&As[srow][sseg + q * 8] = va;
            int4 vb = *(const int4*)(BmT + (size_t)(n0 + srow) * 256 + k0 + sseg + q * 8);
            *(int4*)&Bs[srow][sseg + q * 8] = vb;
        }
        __syncthreads();
#pragma unroll
        for (int ks = 0; ks < 2; ++ks) {
            short8 Af[4], Bf[4];
#pragma unroll
            for (int rf = 0; rf < 4; ++rf)
                Af[rf] = ld_frag(&As[wr * 64 + rf * 16 + li][ks * 32 + g16 * 4]);
#pragma unroll
            for (int cf = 0; cf < 4; ++cf)
                Bf[cf] = ld_frag(&Bs[wc * 64 + cf * 16 + li][ks * 32 + g16 * 4]);
#pragma unroll
            for (int rf = 0; rf < 4; ++rf)
#pragma unroll
                for (int cf = 0; cf < 4; ++cf)
                    acc[rf][cf] = __builtin_amdgcn_mfma_f32_16x16x32_bf16(Af[rf], Bf[cf], acc[rf][cf], 0, 0, 0);
        }
    }
#pragma unroll
    for (int rf = 0; rf < 4; ++rf)
#pragma unroll
        for (int cf = 0; cf < 4; ++cf) {
            const int n = n0 + wc * 64 + cf * 16 + li;
#pragma unroll
            for (int reg = 0; reg < 4; ++reg) {
                const int m = m0 + wr * 64 + rf * 16 + g16 * 4 + reg;
                float v = acc[rf][cf][reg];
                if (n < 256) h[(size_t)m * 256 + n] = v;
                else gate[(size_t)m * 256 + (n - 256)] = sigmoidf_(v + Hb[n - 256]);
            }
        }
}

// ---------------- transpose-cast h->hT + a_src/a_dst partial dots + mean partials ----------------
__global__ __launch_bounds__(256) void tr64f_kernel(const float* __restrict__ h,
                                                    const float* __restrict__ Ws,
                                                    unsigned short* __restrict__ hT,
                                                    float* __restrict__ a_src,
                                                    float* __restrict__ a_dst,
                                                    float* __restrict__ mean_h) {
    __shared__ float tile[64][65];
    const int j0 = blockIdx.x * 64, d0 = blockIdx.y * 64, b = blockIdx.z;
    const int tid = threadIdx.x;
#pragma unroll
    for (int p = 0; p < 16; ++p) {
        int idx = tid + p * 256;
        int jl = idx >> 6, dl = idx & 63;
        tile[jl][dl] = h[((size_t)b * Nc + j0 + jl) * 256 + d0 + dl];
    }
    __syncthreads();
#pragma unroll
    for (int p = 0; p < 16; ++p) {
        int idx = tid + p * 256;
        int dl = idx >> 6, jl = idx & 63;
        hT[((size_t)b * 256 + d0 + dl) * Nc + j0 + jl] = f2bf(tile[jl][dl]);
    }
    { // a_src/a_dst partial dot
        const int jl = tid >> 2, q = tid & 3;
        float s1 = 0.f, s2 = 0.f;
#pragma unroll
        for (int e = 0; e < 16; ++e) {
            const float hv = tile[jl][q * 16 + e];
            s1 = fmaf(hv, Ws[d0 + q * 16 + e], s1);
            s2 = fmaf(hv, Ws[256 + d0 + q * 16 + e], s2);
        }
        s1 += __shfl_xor(s1, 1); s1 += __shfl_xor(s1, 2);
        s2 += __shfl_xor(s2, 1); s2 += __shfl_xor(s2, 2);
        if (q == 0) {
            atomicAdd(&a_src[b * Nc + j0 + jl], s1);
            atomicAdd(&a_dst[b * Nc + j0 + jl], s2);
        }
    }
    { // mean partial
        const int dl = tid & 63, part = tid >> 6;
        float sm = 0.f;
#pragma unroll
        for (int e = 0; e < 16; ++e) sm += tile[part * 16 + e][dl];
        atomicAdd(&mean_h[b * 256 + d0 + dl], sm);
    }
}

// ---------------- zero I_A_raw cols >= i0+32 (diag-tile zeros written by score) ----------------
__global__ __launch_bounds__(256) void fill_kernel(float* __restrict__ out2) {
    const int b = blockIdx.x & 7, ib = blockIdx.x >> 3;
    const int j0 = (ib + 1) * 32;
    if (j0 >= Nc) return;
    const int i0 = ib * 32;
    const int w4 = (Nc - j0) >> 2;
    const float4 z = make_float4(0.f, 0.f, 0.f, 0.f);
    for (int r = 0; r < 32; ++r) {
        float4* row = (float4*)(out2 + ((size_t)b * Nc + i0 + r) * Nc + j0);
        for (int jc = threadIdx.x; jc < w4; jc += 256) row[jc] = z;
    }
}

// ---------------- chunked score: 64-col iters, prefetch, lgkm-only barriers ----------------
constexpr int CHUNK = 8;
__global__ __launch_bounds__(256) void score64(
    const int* __restrict__ adj, const unsigned short* __restrict__ hT,
    const float* __restrict__ a_src, const float* __restrict__ a_dst,
    const float* __restrict__ bs_p, float* __restrict__ out2,
    float* __restrict__ accO, float* __restrict__ sArr) {
    __shared__ unsigned short pt[32][72]; // [row r][col 64 + pad 8]
    __shared__ float sh_as[32];

    // decode block -> (b, ib, c)  [R4-proven balanced chunking]
    const int bid = blockIdx.x;
    const int b = bid & 7; // batch -> XCD affinity
    int t = bid >> 3;      // 0..287
    int g = 0;
    while (g < 7 && 4 * (g + 1) * (g + 2) <= t) ++g;
    const int r_ = t - 4 * g * (g + 1);
    const int ib = g * 8 + r_ / (g + 1);
    const int c = r_ % (g + 1);
    const int i0 = ib * 32;
    const int t0 = c * CHUNK;
    const int t1 = min(ib + 1, t0 + CHUNK);

    const int tid = threadIdx.x, lane = tid & 63, w = tid >> 6;
    const int g16 = lane >> 4, li = lane & 15;
    const int jj = tid & 31, r0 = tid >> 5;
    const float bsv = bs_p[0];

    if (tid < 32) sh_as[tid] = a_src[b * Nc + i0 + tid];
    __syncthreads();
    float asv[4];
#pragma unroll
    for (int q = 0; q < 4; ++q) asv[q] = sh_as[r0 + 8 * q];

    const int* adjb = adj + (size_t)b * Nc * Nc;
    const float* adb = a_dst + b * Nc;
    const unsigned short* hTb = hT + (size_t)b * 256 * Nc;

    f32x4 acc[2][4];
#pragma unroll
    for (int rf = 0; rf < 2; ++rf)
#pragma unroll
        for (int cf = 0; cf < 4; ++cf) acc[rf][cf] = fz4();
    f32x4 sacc0 = fz4(), sacc1 = fz4();
    short8 ones;
#pragma unroll
    for (int e = 0; e < 8; ++e) ones[e] = (short)0x3F80; // bf16 1.0

    int pre_aj[2][4];
    float pre_ad[2];
#define PREF(TT, NS)                                                                   \
    {                                                                                  \
        _Pragma("unroll") for (int s = 0; s < 2; ++s) if (s < (NS)) {                  \
            pre_ad[s] = adb[((TT) + s) * 32 + jj];                                     \
            _Pragma("unroll") for (int q = 0; q < 4; ++q)                              \
                pre_aj[s][q] = adjb[(size_t)(i0 + r0 + 8 * q) * Nc + ((TT) + s) * 32 + jj]; \
        }                                                                              \
    }

    PREF(t0, min(2, t1 - t0));
    for (int tt = t0; tt < t1; tt += 2) {
        const int ns = min(2, t1 - tt);
        int aj_[2][4];
        float ad_[2];
#pragma unroll
        for (int s = 0; s < 2; ++s) {
            ad_[s] = pre_ad[s];
#pragma unroll
            for (int q = 0; q < 4; ++q) aj_[s][q] = pre_aj[s][q];
        }
        if (tt + 2 < t1) PREF(tt + 2, min(2, t1 - tt - 2));
        // B fragments: independent of pt -> issue before barrier, consumed by MFMA phase
        short8 Bf[2][4];
#pragma unroll
        for (int s = 0; s < 2; ++s)
            if (s < ns) {
#pragma unroll
                for (int cf = 0; cf < 4; ++cf)
                    Bf[s][cf] = ld_frag(hTb + (size_t)(w * 64 + cf * 16 + li) * Nc + (tt + s) * 32 + g16 * 4);
            }
        // score phase: thread (r0,jj) -> rows r0+8q, col jj of each 32-col subtile
#pragma unroll
        for (int s = 0; s < 2; ++s)
            if (s < ns) {
                const int jt = tt + s;
                const int j = jt * 32 + jj;
                const bool dia = (jt == ib);
#pragma unroll
                for (int q = 0; q < 4; ++q) {
                    const int r = r0 + 8 * q;
                    const int irow = i0 + r;
                    const float IA = -__builtin_amdgcn_rcpf(1.f + __expf(-(asv[q] + ad_[s] + bsv)));
                    float o2v, p;
                    if (dia && j > irow) { o2v = 0.f; p = 0.f; }
                    else if (dia && j == irow) { o2v = 1.f; p = (aj_[s][q] == 1) ? 1.f : 0.f; }
                    else { o2v = IA; p = (aj_[s][q] == 1) ? __expf(IA - 1.f) : 0.f; }
                    out2[((size_t)b * Nc + irow) * Nc + j] = o2v;
                    pt[r][s * 32 + jj] = f2bf(p);
                }
            }
        lds_barrier(); // pt ready (out2 stores remain in flight)
#pragma unroll
        for (int s = 0; s < 2; ++s)
            if (s < ns) {
                short8 A0 = ld_frag(&pt[li][s * 32 + g16 * 4]);
                short8 A1 = ld_frag(&pt[16 + li][s * 32 + g16 * 4]);
                if (w == 0) {
                    sacc0 = __builtin_amdgcn_mfma_f32_16x16x32_bf16(A0, ones, sacc0, 0, 0, 0);
                    sacc1 = __builtin_amdgcn_mfma_f32_16x16x32_bf16(A1, ones, sacc1, 0, 0, 0);
                }
#pragma unroll
                for (int cf = 0; cf < 4; ++cf) {
                    acc[0][cf] = __builtin_amdgcn_mfma_f32_16x16x32_bf16(A0, Bf[s][cf], acc[0][cf], 0, 0, 0);
                    acc[1][cf] = __builtin_amdgcn_mfma_f32_16x16x32_bf16(A1, Bf[s][cf], acc[1][cf], 0, 0, 0);
                }
            }
        lds_barrier(); // pt consumed; safe to overwrite next iter
    }
#undef PREF
    // combine partial O (atomics; accO pre-zeroed)
#pragma unroll
    for (int rf = 0; rf < 2; ++rf)
#pragma unroll
        for (int cf = 0; cf < 4; ++cf) {
            float* dst = accO + ((size_t)b * Nc + i0 + rf * 16 + g16 * 4) * 256 + w * 64 + cf * 16 + li;
#pragma unroll
            for (int reg = 0; reg < 4; ++reg)
                atomicAdd(dst + (size_t)reg * 256, acc[rf][cf][reg]);
        }
    if (w == 0 && li == 0) { // ones-MFMA row sums: C row = g16*4+reg, any col
#pragma unroll
        for (int reg = 0; reg < 4; ++reg) {
            atomicAdd(&sArr[b * Nc + i0 + g16 * 4 + reg], sacc0[reg]);
            atomicAdd(&sArr[b * Nc + i0 + 16 + g16 * 4 + reg], sacc1[reg]);
        }
    }
}

// ---------------- epilogue: normalize / mean-fallback, +b, ELU, gate mix ----------------
__global__ __launch_bounds__(256) void epilogue_kernel(
    const float* __restrict__ gate, const float* __restrict__ feat,
    const float* __restrict__ bvec, const float* __restrict__ mean_h,
    const float* __restrict__ sArr, float* __restrict__ out1) {
    const int row = blockIdx.x * 4 + (threadIdx.x >> 6);
    const int lane = threadIdx.x & 63;
    const int b = row >> 11;
    const size_t g = (size_t)row * 256;
    const float s = sArr[row];
    float4 v;
    if (s == 0.f) { // fully-masked row: softmax uniform over ALL N cols
        float4 mh = ((const float4*)(mean_h + b * 256))[lane];
        const float inv = 1.0f / Nc;
        v.x = mh.x * inv; v.y = mh.y * inv; v.z = mh.z * inv; v.w = mh.w * inv;
    } else {
        float4 a = ((const float4*)(out1 + g))[lane];
        const float inv = 1.0f / s;
        v.x = a.x * inv; v.y = a.y * inv; v.z = a.z * inv; v.w = a.w * inv;
    }
    const float4 b4 = ((const float4*)bvec)[lane];
    v.x += b4.x; v.y += b4.y; v.z += b4.z; v.w += b4.w;
    v.x = v.x > 0.f ? v.x : __expf(v.x) - 1.f;
    v.y = v.y > 0.f ? v.y : __expf(v.y) - 1.f;
    v.z = v.z > 0.f ? v.z : __expf(v.z) - 1.f;
    v.w = v.w > 0.f ? v.w : __expf(v.w) - 1.f;
    const float4 g4 = ((const float4*)(gate + g))[lane];
    const float4 f4 = ((const float4*)(feat + g))[lane];
    float4 o;
    o.x = g4.x * v.x + (1.f - g4.x) * f4.x;
    o.y = g4.y * v.y + (1.f - g4.y) * f4.y;
    o.z = g4.z * v.z + (1.f - g4.z) * f4.z;
    o.w = g4.w * v.w + (1.f - g4.w) * f4.w;
    ((float4*)(out1 + g))[lane] = o;
}

extern "C" void kernel_launch(void* const* d_in, const int* in_sizes, int n_in,
                              void* d_out, int out_size, void* d_ws, size_t ws_size,
                              hipStream_t stream) {
    const float* feat = (const float*)d_in[0];
    const int* adj = (const int*)d_in[1];
    const float* W = (const float*)d_in[2];
    const float* bvec = (const float*)d_in[3];
    const float* Ws = (const float*)d_in[4];
    const float* bs = (const float*)d_in[5];
    const float* Hw = (const float*)d_in[6];
    const float* Hb = (const float*)d_in[7];

    float* ws = (float*)d_ws;
    unsigned short* featb = (unsigned short*)ws; // bf16 16384x256; reused as hT after gemm
    unsigned short* hT = featb;
    unsigned short* BmT = featb + 4194304;       // bf16 512x256
    float* h = ws + 2097152 + 65536;             // fp32 16384x256
    float* gate = h + 4194304;                   // fp32 16384x256
    float* a_src = gate + 4194304;               // 16384
    float* a_dst = a_src + 16384;                // 16384
    float* mean_h = a_dst + 16384;               // 2048
    float* sArr = mean_h + 2048;                 // 16384

    float* out1 = (float*)d_out;
    float* out2 = out1 + (size_t)BN * 256;

    hipLaunchKernelGGL(cast_kernel, dim3(4096), dim3(256), 0, stream, feat, featb);
    hipLaunchKernelGGL(pack_bt_kernel, dim3(512), dim3(256), 0, stream, W, Hw, BmT);
    hipLaunchKernelGGL(gemm_lds, dim3(128, 4), dim3(256), 0, stream, featb, BmT, Hb, h, gate);
    hipMemsetAsync(a_src, 0, (16384 + 16384 + 2048 + 16384) * sizeof(float), stream);
    hipLaunchKernelGGL(tr64f_kernel, dim3(32, 4, 8), dim3(256), 0, stream,
                       h, Ws, hT, a_src, a_dst, mean_h);
    hipMemsetAsync(out1, 0, (size_t)BN * 256 * sizeof(float), stream); // accO zero
    hipLaunchKernelGGL(fill_kernel, dim3(512), dim3(256), 0, stream, out2);
    hipLaunchKernelGGL(score64, dim3(2304), dim3(256), 0, stream,
                       adj, hT, a_src, a_dst, bs, out2, out1, sArr);
    hipLaunchKernelGGL(epilogue_kernel, dim3(4096), dim3(256), 0, stream,
                       gate, feat, bvec, mean_h, sArr, out1);
}

// Round 9
// 387.952 us; speedup vs baseline: 2.0872x; 1.0036x over previous
//
#include <hip/hip_runtime.h>
#include <math.h>

constexpr int Bc = 8, Nc = 2048, Dc = 256;
constexpr int BN = Bc * Nc; // 16384

typedef __attribute__((ext_vector_type(8))) short short8;
typedef __attribute__((ext_vector_type(4))) float f32x4;

__device__ __forceinline__ float sigmoidf_(float x) { return 1.0f / (1.0f + expf(-x)); }

__device__ __forceinline__ unsigned short f2bf(float f) { // RNE fp32 -> bf16
    unsigned int u = __float_as_uint(f);
    u = (u + 0x7FFFu + ((u >> 16) & 1u)) >> 16;
    return (unsigned short)u;
}
__device__ __forceinline__ float bf2f(unsigned short s) {
    return __uint_as_float(((unsigned int)s) << 16);
}

// 8-elem bf16 fragment: elems 0..3 at base[0..3], elems 4..7 at base[16..19].
// k-slot bijection slot(g16,e): e<4 -> g16*4+e ; e>=4 -> 16+g16*4+(e-4).
// A and B fragments both use it => consistent pairing (any bijection valid).
__device__ __forceinline__ short8 ld_frag(const unsigned short* base) {
    ushort4 lo = *(const ushort4*)(base);
    ushort4 hi = *(const ushort4*)(base + 16);
    short8 a;
    a[0] = (short)lo.x; a[1] = (short)lo.y; a[2] = (short)lo.z; a[3] = (short)lo.w;
    a[4] = (short)hi.x; a[5] = (short)hi.y; a[6] = (short)hi.z; a[7] = (short)hi.w;
    return a;
}
__device__ __forceinline__ f32x4 fz4() { f32x4 z = {0.f, 0.f, 0.f, 0.f}; return z; }

// lgkm-only barrier: drains LDS ops but NOT pending global stores/loads (vmcnt),
// so out2 stores and prefetches stay in flight across it. Rule #18: sched_barrier after.
__device__ __forceinline__ void lds_barrier() {
    asm volatile("s_waitcnt lgkmcnt(0)" ::: "memory");
    __builtin_amdgcn_s_barrier();
    __builtin_amdgcn_sched_barrier(0);
}

// ---------------- pack BmT[512 n][256 k] bf16 = [ W | Hw^T ]^T ----------------
__global__ __launch_bounds__(256) void pack_bt_kernel(const float* __restrict__ W,
                                                      const float* __restrict__ Hw,
                                                      unsigned short* __restrict__ BmT) {
    int idx = blockIdx.x * 256 + threadIdx.x;
    int o = idx >> 8, k = idx & 255;
    float v = (o < 256) ? W[k * 256 + o] : Hw[(o - 256) * 256 + k];
    BmT[idx] = f2bf(v);
}

// ---------------- LDS-staged MFMA GEMM, feat fp32 cast in staging; h|gate epilogue ------
__global__ __launch_bounds__(256) void gemm_lds(const float* __restrict__ featf,
                                                const unsigned short* __restrict__ BmT,
                                                const float* __restrict__ Hb,
                                                float* __restrict__ h,
                                                float* __restrict__ gate) {
    __shared__ unsigned short As[128][72]; // stride 72: spreads banks for b64 reads
    __shared__ unsigned short Bs[128][72];
    const int tid = threadIdx.x, lane = tid & 63, w = tid >> 6;
    const int g16 = lane >> 4, li = lane & 15;
    const int wr = w >> 1, wc = w & 1; // wave quadrant (64x64)
    const int m0 = blockIdx.x * 128, n0 = blockIdx.y * 128;
    const int srow = tid >> 1, fseg = (tid & 1) * 32; // staging row / k-seg (elements)
    f32x4 acc[4][4];
#pragma unroll
    for (int rf = 0; rf < 4; ++rf)
#pragma unroll
        for (int cf = 0; cf < 4; ++cf) acc[rf][cf] = fz4();
    for (int k0 = 0; k0 < 256; k0 += 64) {
        if (k0) __syncthreads();
#pragma unroll
        for (int q = 0; q < 8; ++q) { // A: fp32 load + cvt + b64 LDS store
            float4 va = *(const float4*)(featf + (size_t)(m0 + srow) * 256 + k0 + fseg + q * 4);
            ushort4 u = {f2bf(va.x), f2bf(va.y), f2bf(va.z), f2bf(va.w)};
            *(ushort4*)&As[srow][fseg + q * 4] = u;
        }
#pragma unroll
        for (int q = 0; q < 4; ++q) { // B: bf16 16B loads
            int4 vb = *(const int4*)(BmT + (size_t)(n0 + srow) * 256 + k0 + fseg + q * 8);
            *(int4*)&Bs[srow][fseg + q * 8] = vb;
        }
        __syncthreads();
#pragma unroll
        for (int ks = 0; ks < 2; ++ks) {
            short8 Af[4], Bf[4];
#pragma unroll
            for (int rf = 0; rf < 4; ++rf)
                Af[rf] = ld_frag(&As[wr * 64 + rf * 16 + li][ks * 32 + g16 * 4]);
#pragma unroll
            for (int cf = 0; cf < 4; ++cf)
                Bf[cf] = ld_frag(&Bs[wc * 64 + cf * 16 + li][ks * 32 + g16 * 4]);
#pragma unroll
            for (int rf = 0; rf < 4; ++rf)
#pragma unroll
                for (int cf = 0; cf < 4; ++cf)
                    acc[rf][cf] = __builtin_amdgcn_mfma_f32_16x16x32_bf16(Af[rf], Bf[cf], acc[rf][cf], 0, 0, 0);
        }
    }
#pragma unroll
    for (int rf = 0; rf < 4; ++rf)
#pragma unroll
        for (int cf = 0; cf < 4; ++cf) {
            const int n = n0 + wc * 64 + cf * 16 + li;
#pragma unroll
            for (int reg = 0; reg < 4; ++reg) {
                const int m = m0 + wr * 64 + rf * 16 + g16 * 4 + reg;
                float v = acc[rf][cf][reg];
                if (n < 256) h[(size_t)m * 256 + n] = v;
                else gate[(size_t)m * 256 + (n - 256)] = sigmoidf_(v + Hb[n - 256]);
            }
        }
}

// ---------------- transpose-cast h->hT + a_src/a_dst partial dots + mean partials ----------------
__global__ __launch_bounds__(256) void tr64f_kernel(const float* __restrict__ h,
                                                    const float* __restrict__ Ws,
                                                    unsigned short* __restrict__ hT,
                                                    float* __restrict__ a_src,
                                                    float* __restrict__ a_dst,
                                                    float* __restrict__ mean_h) {
    __shared__ float tile[64][65];
    const int j0 = blockIdx.x * 64, d0 = blockIdx.y * 64, b = blockIdx.z;
    const int tid = threadIdx.x;
#pragma unroll
    for (int p = 0; p < 16; ++p) {
        int idx = tid + p * 256;
        int jl = idx >> 6, dl = idx & 63;
        tile[jl][dl] = h[((size_t)b * Nc + j0 + jl) * 256 + d0 + dl];
    }
    __syncthreads();
#pragma unroll
    for (int p = 0; p < 16; ++p) {
        int idx = tid + p * 256;
        int dl = idx >> 6, jl = idx & 63;
        hT[((size_t)b * 256 + d0 + dl) * Nc + j0 + jl] = f2bf(tile[jl][dl]);
    }
    { // a_src/a_dst partial dot
        const int jl = tid >> 2, q = tid & 3;
        float s1 = 0.f, s2 = 0.f;
#pragma unroll
        for (int e = 0; e < 16; ++e) {
            const float hv = tile[jl][q * 16 + e];
            s1 = fmaf(hv, Ws[d0 + q * 16 + e], s1);
            s2 = fmaf(hv, Ws[256 + d0 + q * 16 + e], s2);
        }
        s1 += __shfl_xor(s1, 1); s1 += __shfl_xor(s1, 2);
        s2 += __shfl_xor(s2, 1); s2 += __shfl_xor(s2, 2);
        if (q == 0) {
            atomicAdd(&a_src[b * Nc + j0 + jl], s1);
            atomicAdd(&a_dst[b * Nc + j0 + jl], s2);
        }
    }
    { // mean partial
        const int dl = tid & 63, part = tid >> 6;
        float sm = 0.f;
#pragma unroll
        for (int e = 0; e < 16; ++e) sm += tile[part * 16 + e][dl];
        atomicAdd(&mean_h[b * 256 + d0 + dl], sm);
    }
}

// ---------------- chunked score v2: dbuf pt, 1 barrier/iter, fused upper-fill ----------------
constexpr int CHUNK = 16;
__global__ __launch_bounds__(256) void score64(
    const int* __restrict__ adj, const unsigned short* __restrict__ hT,
    const float* __restrict__ a_src, const float* __restrict__ a_dst,
    const float* __restrict__ bs_p, float* __restrict__ out2,
    float* __restrict__ accO, float* __restrict__ sArr) {
    __shared__ unsigned short pt[2][32][72]; // double-buffered P tile

    // decode block -> (b, ib, c); bands of 16 row-blocks share chunk count g+1
    const int bid = blockIdx.x;
    const int b = bid & 7; // batch -> XCD affinity
    int t = bid >> 3;      // 0..159
    int g = 0;
    while (g < 3 && 8 * (g + 1) * (g + 2) <= t) ++g;
    const int r_ = t - 8 * g * (g + 1);
    const int ib = g * 16 + r_ / (g + 1);
    const int c = r_ % (g + 1);
    const int nch = g + 1;
    const int i0 = ib * 32;
    // balanced split of T=ib+1 tiles over nch chunks
    const int T = ib + 1;
    const int base = T / nch, rem = T % nch;
    const int t0 = c * base + min(c, rem);
    const int t1 = t0 + base + (c < rem ? 1 : 0);

    const int tid = threadIdx.x, lane = tid & 63, w = tid >> 6;
    const int g16 = lane >> 4, li = lane & 15;
    const int jj = tid & 31, r0 = tid >> 5;
    const float bsv = bs_p[0];
    float asv[4];
#pragma unroll
    for (int q = 0; q < 4; ++q) asv[q] = a_src[b * Nc + i0 + r0 + 8 * q];

    const int* adjb = adj + (size_t)b * Nc * Nc;
    const float* adb = a_dst + b * Nc;
    const unsigned short* hTb = hT + (size_t)b * 256 * Nc;

    f32x4 acc[2][4];
#pragma unroll
    for (int rf = 0; rf < 2; ++rf)
#pragma unroll
        for (int cf = 0; cf < 4; ++cf) acc[rf][cf] = fz4();
    f32x4 sacc0 = fz4(), sacc1 = fz4();
    short8 ones;
#pragma unroll
    for (int e = 0; e < 8; ++e) ones[e] = (short)0x3F80; // bf16 1.0

    int pre_aj[2][4];
    float pre_ad[2];
#define PREF(TT, NS)                                                                   \
    {                                                                                  \
        _Pragma("unroll") for (int s = 0; s < 2; ++s) if (s < (NS)) {                  \
            pre_ad[s] = adb[((TT) + s) * 32 + jj];                                     \
            _Pragma("unroll") for (int q = 0; q < 4; ++q)                              \
                pre_aj[s][q] = adjb[(size_t)(i0 + r0 + 8 * q) * Nc + ((TT) + s) * 32 + jj]; \
        }                                                                              \
    }

    PREF(t0, min(2, t1 - t0));
    int p = 0;
    for (int tt = t0; tt < t1; tt += 2, p ^= 1) {
        const int ns = min(2, t1 - tt);
        int aj_[2][4];
        float ad_[2];
#pragma unroll
        for (int s = 0; s < 2; ++s) {
            ad_[s] = pre_ad[s];
#pragma unroll
            for (int q = 0; q < 4; ++q) aj_[s][q] = pre_aj[s][q];
        }
        if (tt + 2 < t1) PREF(tt + 2, min(2, t1 - tt - 2));
        // B fragments: independent of pt -> issue early, consumed by MFMA phase
        short8 Bf[2][4];
#pragma unroll
        for (int s = 0; s < 2; ++s)
            if (s < ns) {
#pragma unroll
                for (int cf = 0; cf < 4; ++cf)
                    Bf[s][cf] = ld_frag(hTb + (size_t)(w * 64 + cf * 16 + li) * Nc + (tt + s) * 32 + g16 * 4);
            }
        // score phase: thread (r0,jj) -> rows r0+8q, col jj of each 32-col subtile
#pragma unroll
        for (int s = 0; s < 2; ++s)
            if (s < ns) {
                const int jt = tt + s;
                const int j = jt * 32 + jj;
                const bool dia = (jt == ib);
#pragma unroll
                for (int q = 0; q < 4; ++q) {
                    const int r = r0 + 8 * q;
                    const int irow = i0 + r;
                    const float IA = -__builtin_amdgcn_rcpf(1.f + __expf(-(asv[q] + ad_[s] + bsv)));
                    float o2v, pp;
                    if (dia && j > irow) { o2v = 0.f; pp = 0.f; }
                    else if (dia && j == irow) { o2v = 1.f; pp = (aj_[s][q] == 1) ? 1.f : 0.f; }
                    else { o2v = IA; pp = (aj_[s][q] == 1) ? __expf(IA - 1.f) : 0.f; }
                    out2[((size_t)b * Nc + irow) * Nc + j] = o2v;
                    pt[p][r][s * 32 + jj] = f2bf(pp);
                }
            }
        lds_barrier(); // pt[p] ready; WAR on pt[p] closed by barriers of iters i, i+1
#pragma unroll
        for (int s = 0; s < 2; ++s)
            if (s < ns) {
                short8 A0 = ld_frag(&pt[p][li][s * 32 + g16 * 4]);
                short8 A1 = ld_frag(&pt[p][16 + li][s * 32 + g16 * 4]);
                if (w == 0) {
                    sacc0 = __builtin_amdgcn_mfma_f32_16x16x32_bf16(A0, ones, sacc0, 0, 0, 0);
                    sacc1 = __builtin_amdgcn_mfma_f32_16x16x32_bf16(A1, ones, sacc1, 0, 0, 0);
                }
#pragma unroll
                for (int cf = 0; cf < 4; ++cf) {
                    acc[0][cf] = __builtin_amdgcn_mfma_f32_16x16x32_bf16(A0, Bf[s][cf], acc[0][cf], 0, 0, 0);
                    acc[1][cf] = __builtin_amdgcn_mfma_f32_16x16x32_bf16(A1, Bf[s][cf], acc[1][cf], 0, 0, 0);
                }
            }
    }
#undef PREF
    // combine partial O (atomics; accO pre-zeroed)
#pragma unroll
    for (int rf = 0; rf < 2; ++rf)
#pragma unroll
        for (int cf = 0; cf < 4; ++cf) {
            float* dst = accO + ((size_t)b * Nc + i0 + rf * 16 + g16 * 4) * 256 + w * 64 + cf * 16 + li;
#pragma unroll
            for (int reg = 0; reg < 4; ++reg)
                atomicAdd(dst + (size_t)reg * 256, acc[rf][cf][reg]);
        }
    if (w == 0 && li == 0) { // ones-MFMA row sums: C row = g16*4+reg
#pragma unroll
        for (int reg = 0; reg < 4; ++reg) {
            atomicAdd(&sArr[b * Nc + i0 + g16 * 4 + reg], sacc0[reg]);
            atomicAdd(&sArr[b * Nc + i0 + 16 + g16 * 4 + reg], sacc1[reg]);
        }
    }
    { // fused upper-triangle zero-fill: chunk c covers its 1/nch slice of cols [i0+32, 2048)
        const int w4beg = (i0 + 32) >> 2;
        const int W4 = 512 - w4beg;
        const int sbeg = w4beg + (int)(((long)W4 * c) / nch);
        const int send = w4beg + (int)(((long)W4 * (c + 1)) / nch);
        const float4 z = make_float4(0.f, 0.f, 0.f, 0.f);
        for (int r = 0; r < 32; ++r) {
            float4* rowp = (float4*)(out2 + ((size_t)b * Nc + i0 + r) * Nc);
            for (int j4 = sbeg + tid; j4 < send; j4 += 256) rowp[j4] = z;
        }
    }
}

// ---------------- epilogue: normalize / mean-fallback, +b, ELU, gate mix ----------------
__global__ __launch_bounds__(256) void epilogue_kernel(
    const float* __restrict__ gate, const float* __restrict__ feat,
    const float* __restrict__ bvec, const float* __restrict__ mean_h,
    const float* __restrict__ sArr, float* __restrict__ out1) {
    const int row = blockIdx.x * 4 + (threadIdx.x >> 6);
    const int lane = threadIdx.x & 63;
    const int b = row >> 11;
    const size_t g = (size_t)row * 256;
    const float s = sArr[row];
    float4 v;
    if (s == 0.f) { // fully-masked row: softmax uniform over ALL N cols
        float4 mh = ((const float4*)(mean_h + b * 256))[lane];
        const float inv = 1.0f / Nc;
        v.x = mh.x * inv; v.y = mh.y * inv; v.z = mh.z * inv; v.w = mh.w * inv;
    } else {
        float4 a = ((const float4*)(out1 + g))[lane];
        const float inv = 1.0f / s;
        v.x = a.x * inv; v.y = a.y * inv; v.z = a.z * inv; v.w = a.w * inv;
    }
    const float4 b4 = ((const float4*)bvec)[lane];
    v.x += b4.x; v.y += b4.y; v.z += b4.z; v.w += b4.w;
    v.x = v.x > 0.f ? v.x : __expf(v.x) - 1.f;
    v.y = v.y > 0.f ? v.y : __expf(v.y) - 1.f;
    v.z = v.z > 0.f ? v.z : __expf(v.z) - 1.f;
    v.w = v.w > 0.f ? v.w : __expf(v.w) - 1.f;
    const float4 g4 = ((const float4*)(gate + g))[lane];
    const float4 f4 = ((const float4*)(feat + g))[lane];
    float4 o;
    o.x = g4.x * v.x + (1.f - g4.x) * f4.x;
    o.y = g4.y * v.y + (1.f - g4.y) * f4.y;
    o.z = g4.z * v.z + (1.f - g4.z) * f4.z;
    o.w = g4.w * v.w + (1.f - g4.w) * f4.w;
    ((float4*)(out1 + g))[lane] = o;
}

extern "C" void kernel_launch(void* const* d_in, const int* in_sizes, int n_in,
                              void* d_out, int out_size, void* d_ws, size_t ws_size,
                              hipStream_t stream) {
    const float* feat = (const float*)d_in[0];
    const int* adj = (const int*)d_in[1];
    const float* W = (const float*)d_in[2];
    const float* bvec = (const float*)d_in[3];
    const float* Ws = (const float*)d_in[4];
    const float* bs = (const float*)d_in[5];
    const float* Hw = (const float*)d_in[6];
    const float* Hb = (const float*)d_in[7];

    float* ws = (float*)d_ws;
    unsigned short* hT = (unsigned short*)ws;    // bf16 8x256x2048
    unsigned short* BmT = hT + 4194304;          // bf16 512x256
    float* h = ws + 2097152 + 65536;             // fp32 16384x256
    float* gate = h + 4194304;                   // fp32 16384x256
    float* a_src = gate + 4194304;               // 16384
    float* a_dst = a_src + 16384;                // 16384
    float* mean_h = a_dst + 16384;               // 2048
    float* sArr = mean_h + 2048;                 // 16384

    float* out1 = (float*)d_out;
    float* out2 = out1 + (size_t)BN * 256;

    hipMemsetAsync(a_src, 0, (16384 + 16384 + 2048 + 16384) * sizeof(float), stream);
    hipLaunchKernelGGL(pack_bt_kernel, dim3(512), dim3(256), 0, stream, W, Hw, BmT);
    hipLaunchKernelGGL(gemm_lds, dim3(128, 4), dim3(256), 0, stream, feat, BmT, Hb, h, gate);
    hipLaunchKernelGGL(tr64f_kernel, dim3(32, 4, 8), dim3(256), 0, stream,
                       h, Ws, hT, a_src, a_dst, mean_h);
    hipMemsetAsync(out1, 0, (size_t)BN * 256 * sizeof(float), stream); // accO zero
    hipLaunchKernelGGL(score64, dim3(1280), dim3(256), 0, stream,
                       adj, hT, a_src, a_dst, bs, out2, out1, sArr);
    hipLaunchKernelGGL(epilogue_kernel, dim3(4096), dim3(256), 0, stream,
                       gate, feat, bvec, mean_h, sArr, out1);
}